// Round 10
// baseline (3406.934 us; speedup 1.0000x reference)
//
#include <hip/hip_runtime.h>
#include <stdint.h>

#define T_DIM 8192
#define C_DIM 2048
#define LCHUNK 128
#define NCHUNK (T_DIM / LCHUNK)

typedef unsigned short u16;
typedef __bf16 bf16x8_t __attribute__((ext_vector_type(8)));
typedef float f32x4_t __attribute__((ext_vector_type(4)));

__device__ __forceinline__ u16 f2bf(float f) {
    union { float f; uint32_t u; } x; x.f = f;
    uint32_t r = x.u + 0x7fffu + ((x.u >> 16) & 1u);
    return (u16)(r >> 16);
}
__device__ __forceinline__ float bf2f(u16 u) {
    union { uint32_t u; float f; } x; x.u = ((uint32_t)u) << 16;
    return x.f;
}
__device__ __forceinline__ void gload16(const void* g, void* l) {
    __builtin_amdgcn_global_load_lds((const __attribute__((address_space(1))) uint32_t*)g,
                                     (__attribute__((address_space(3))) uint32_t*)l, 16, 0, 0);
}
__device__ __forceinline__ f32x4_t mfma16(bf16x8_t a, bf16x8_t b, f32x4_t c) {
    return __builtin_amdgcn_mfma_f32_16x16x32_bf16(a, b, c, 0, 0, 0);
}

// ---- shared helper: 32x32 weight transpose tile: Wt[n][k] = bf16(W[k][n]) ----
__device__ __forceinline__ void transpose_tile(const float* __restrict__ W, u16* __restrict__ Tm,
                                               int bn, int bk, float* shf)
{
    const int tid = threadIdx.x;
    const int tx = tid & 31, ty = tid >> 5;
#pragma unroll
    for (int i = 0; i < 4; ++i)
        shf[(ty + 8 * i) * 33 + tx] = W[(size_t)(bk + ty + 8 * i) * C_DIM + bn + tx];
    __syncthreads();
#pragma unroll
    for (int i = 0; i < 4; ++i)
        Tm[(size_t)(bn + ty + 8 * i) * C_DIM + bk + tx] = f2bf(shf[tx * 33 + ty + 8 * i]);
}

// ---------------- prep: ln_mix (blocks 0..8191) U transpose Wk,Wv,Wr (blocks 8192..20479) --------
union F8 { float4 v[2]; float f[8]; };

__global__ __launch_bounds__(256)
void prep_kernel(const float* __restrict__ W0, const float* __restrict__ W1,
                 const float* __restrict__ W2, u16* __restrict__ Wt,
                 const float* __restrict__ x, const float* __restrict__ sx,
                 const float* __restrict__ lns, const float* __restrict__ lnb,
                 const float* __restrict__ tmk, const float* __restrict__ tmv,
                 const float* __restrict__ tmr,
                 u16* __restrict__ kx, u16* __restrict__ vx, u16* __restrict__ rx,
                 float* __restrict__ xx_last)
{
    __shared__ float shf[32 * 33];
    const int bid = blockIdx.x;
    const int tid = threadIdx.x;

    if (bid >= 8192) {
        const int z = (bid - 8192) >> 12;
        const int rem = (bid - 8192) & 4095;
        const float* W = (z == 0) ? W0 : (z == 1) ? W1 : W2;
        transpose_tile(W, Wt + (size_t)z * C_DIM * C_DIM, (rem & 63) * 32, (rem >> 6) * 32, shf);
        return;
    }

    const int t = bid;
    const size_t rowoff = (size_t)t * C_DIM;

    F8 a, p;
    const float4* xt = (const float4*)(x + rowoff);
    a.v[0] = xt[2 * tid]; a.v[1] = xt[2 * tid + 1];
    const float4* xp = (t == 0) ? (const float4*)sx : (const float4*)(x + rowoff - C_DIM);
    p.v[0] = xp[2 * tid]; p.v[1] = xp[2 * tid + 1];

    float s1 = 0.f, s2 = 0.f, s3 = 0.f, s4 = 0.f;
#pragma unroll
    for (int i = 0; i < 8; ++i) {
        s1 += a.f[i]; s2 += a.f[i] * a.f[i];
        s3 += p.f[i]; s4 += p.f[i] * p.f[i];
    }
#pragma unroll
    for (int off = 32; off; off >>= 1) {
        s1 += __shfl_down(s1, off);
        s2 += __shfl_down(s2, off);
        s3 += __shfl_down(s3, off);
        s4 += __shfl_down(s4, off);
    }
    float* red = shf;
    if ((tid & 63) == 0) {
        red[0 * 4 + (tid >> 6)] = s1; red[1 * 4 + (tid >> 6)] = s2;
        red[2 * 4 + (tid >> 6)] = s3; red[3 * 4 + (tid >> 6)] = s4;
    }
    __syncthreads();
    s1 = red[0] + red[1] + red[2] + red[3];
    s2 = red[4] + red[5] + red[6] + red[7];
    s3 = red[8] + red[9] + red[10] + red[11];
    s4 = red[12] + red[13] + red[14] + red[15];
    const float inv = 1.0f / (float)C_DIM;
    const float mu = s1 * inv;
    const float rstd = rsqrtf(s2 * inv - mu * mu + 1e-5f);
    const float mup = s3 * inv;
    const float rstdp = rsqrtf(s4 * inv - mup * mup + 1e-5f);

    F8 ls, lb, mk, mv, mr;
    { const float4* q = (const float4*)lns; ls.v[0] = q[2*tid]; ls.v[1] = q[2*tid+1]; }
    { const float4* q = (const float4*)lnb; lb.v[0] = q[2*tid]; lb.v[1] = q[2*tid+1]; }
    { const float4* q = (const float4*)tmk; mk.v[0] = q[2*tid]; mk.v[1] = q[2*tid+1]; }
    { const float4* q = (const float4*)tmv; mv.v[0] = q[2*tid]; mv.v[1] = q[2*tid+1]; }
    { const float4* q = (const float4*)tmr; mr.v[0] = q[2*tid]; mr.v[1] = q[2*tid+1]; }

    union { u16 u[8]; uint4 q; } ok, ov, orr;
#pragma unroll
    for (int i = 0; i < 8; ++i) {
        const float xxv  = (a.f[i] - mu) * rstd * ls.f[i] + lb.f[i];
        const float prev = (t == 0) ? p.f[i] : (p.f[i] - mup) * rstdp * ls.f[i] + lb.f[i];
        ok.u[i]  = f2bf(xxv * mk.f[i] + prev * (1.f - mk.f[i]));
        ov.u[i]  = f2bf(xxv * mv.f[i] + prev * (1.f - mv.f[i]));
        orr.u[i] = f2bf(xxv * mr.f[i] + prev * (1.f - mr.f[i]));
        if (t == T_DIM - 1) xx_last[tid * 8 + i] = xxv;
    }
    ((uint4*)(kx + rowoff))[tid] = ok.q;
    ((uint4*)(vx + rowoff))[tid] = ov.q;
    ((uint4*)(rx + rowoff))[tid] = orr.q;
}

// ---------------- single-buffered GEMM core: 128x128 tile, BK=32, 16 KiB LDS ----------------
// m97 structure: stage -> sync -> ds_read+MFMA -> sync. All cross-iteration overlap comes
// from co-resident blocks (8/CU at launch_bounds(256,8)). Swizzle as r8 (0 conflicts).
__device__ __forceinline__ void gemm_core_sb(
    const u16* __restrict__ A, const u16* __restrict__ Bt,
    void* __restrict__ Cout, const int mode, const int N, const int K,
    const int m0, const int n0, u16* lds)
{
    const int tid = threadIdx.x;
    const int wave = tid >> 6, lane = tid & 63;
    const int wm = wave >> 1, wn = wave & 1;
    const int fr = lane & 15, fo = lane >> 4;
    const int sw = (fo ^ ((fr >> 1) & 3)) * 8;

    f32x4_t acc[4][4] = {};

    const int lrow = lane >> 2;
    const int scol = ((lane & 3) ^ ((lane >> 3) & 3)) * 8;
    const u16* gA = A  + (size_t)(m0 + wave * 16 + lrow) * K + scol;
    const u16* gB = Bt + (size_t)(n0 + wave * 16 + lrow) * K + scol;
    const size_t rk64 = (size_t)64 * K;
    const int dA = wave * 512;
    const int dB = 4096 + wave * 512;

    const int NT = K >> 5;
    for (int t = 0; t < NT; ++t) {
        const u16* ga = gA + (size_t)t * 32;
        const u16* gb = gB + (size_t)t * 32;
        gload16(ga,        lds + dA);
        gload16(ga + rk64, lds + dA + 2048);
        gload16(gb,        lds + dB);
        gload16(gb + rk64, lds + dB + 2048);
        __syncthreads();                       // stage landed (vmcnt0 + barrier)
        const u16* lA = lds + (wm * 64 + fr) * 32;
        const u16* lB = lds + 4096 + (wn * 64 + fr) * 32;
        bf16x8_t a[4], b[4];
#pragma unroll
        for (int i = 0; i < 4; ++i) {
            a[i] = *(const bf16x8_t*)(lA + i * 512 + sw);
            b[i] = *(const bf16x8_t*)(lB + i * 512 + sw);
        }
        __builtin_amdgcn_s_setprio(1);
#pragma unroll
        for (int mi = 0; mi < 4; ++mi)
#pragma unroll
            for (int ni = 0; ni < 4; ++ni)
                acc[mi][ni] = mfma16(a[mi], b[ni], acc[mi][ni]);
        __builtin_amdgcn_s_setprio(0);
        __syncthreads();                       // all ds_reads consumed before next stage
    }

    const int r4 = fo * 4;
#pragma unroll
    for (int mi = 0; mi < 4; ++mi) {
#pragma unroll
        for (int ni = 0; ni < 4; ++ni) {
            const int col = n0 + wn * 64 + ni * 16 + fr;
#pragma unroll
            for (int i = 0; i < 4; ++i) {
                const int row = m0 + wm * 64 + mi * 16 + r4 + i;
                float v = acc[mi][ni][i];
                if (mode == 1) ((u16*)Cout)[(size_t)row * N + col] = f2bf(v);
                else {
                    const float s = 1.f / (1.f + __expf(-v));
                    ((u16*)Cout)[(size_t)row * N + col] = f2bf(s);
                }
            }
        }
    }
}

// ---------------- dbuf GEMM core (r8-proven, 32 KiB, 4 blocks/CU) for gemm_o ----------------
__device__ __forceinline__ void gemm_core_db(
    const u16* __restrict__ A, const u16* __restrict__ Bt,
    float* __restrict__ Cout, const float* __restrict__ resid,
    const int N, const int K, const int m0, const int n0, u16* lds)
{
    const int tid = threadIdx.x;
    const int wave = tid >> 6, lane = tid & 63;
    const int wm = wave >> 1, wn = wave & 1;
    const int fr = lane & 15, fo = lane >> 4;
    const int sw = (fo ^ ((fr >> 1) & 3)) * 8;

    f32x4_t acc[4][4] = {};

    const int lrow = lane >> 2;
    const int scol = ((lane & 3) ^ ((lane >> 3) & 3)) * 8;
    const u16* gA = A  + (size_t)(m0 + wave * 16 + lrow) * K + scol;
    const u16* gB = Bt + (size_t)(n0 + wave * 16 + lrow) * K + scol;
    const size_t rk64 = (size_t)64 * K;
    const int dA = wave * 512;
    const int dB = 4096 + wave * 512;

    auto stage = [&](int t) {
        const int b = (t & 1) * 8192;
        const u16* ga = gA + (size_t)t * 32;
        const u16* gb = gB + (size_t)t * 32;
        gload16(ga,        lds + b + dA);
        gload16(ga + rk64, lds + b + dA + 2048);
        gload16(gb,        lds + b + dB);
        gload16(gb + rk64, lds + b + dB + 2048);
    };

    const int NT = K >> 5;
    stage(0);
    asm volatile("s_waitcnt vmcnt(0)" ::: "memory");
    asm volatile("s_barrier" ::: "memory");

    for (int t = 0; t < NT; ++t) {
        if (t + 1 < NT) stage(t + 1);
        const u16* lA = lds + (t & 1) * 8192 + (wm * 64 + fr) * 32;
        const u16* lB = lds + (t & 1) * 8192 + 4096 + (wn * 64 + fr) * 32;
        bf16x8_t a[4], b[4];
#pragma unroll
        for (int i = 0; i < 4; ++i) {
            a[i] = *(const bf16x8_t*)(lA + i * 512 + sw);
            b[i] = *(const bf16x8_t*)(lB + i * 512 + sw);
        }
        __builtin_amdgcn_s_setprio(1);
#pragma unroll
        for (int mi = 0; mi < 4; ++mi)
#pragma unroll
            for (int ni = 0; ni < 4; ++ni)
                acc[mi][ni] = mfma16(a[mi], b[ni], acc[mi][ni]);
        __builtin_amdgcn_s_setprio(0);
        asm volatile("s_waitcnt vmcnt(0)" ::: "memory");
        asm volatile("s_barrier" ::: "memory");
    }

    const int r4 = fo * 4;
#pragma unroll
    for (int mi = 0; mi < 4; ++mi) {
#pragma unroll
        for (int ni = 0; ni < 4; ++ni) {
            const int col = n0 + wn * 64 + ni * 16 + fr;
#pragma unroll
            for (int i = 0; i < 4; ++i) {
                const int row = m0 + wm * 64 + mi * 16 + r4 + i;
                Cout[(size_t)row * N + col] = acc[mi][ni][i] + resid[(size_t)row * N + col];
            }
        }
    }
}

// k,v,r GEMMs (blocks 0..3071) U Wo transpose (blocks 3072..7167). 8 blocks/CU.
__global__ __launch_bounds__(256, 8)
void gemm_kvr(const u16* __restrict__ kx, const u16* __restrict__ vx, const u16* __restrict__ rxp,
              const float* __restrict__ Wo, u16* __restrict__ Wt,
              u16* __restrict__ kbuf, u16* __restrict__ vbuf, u16* __restrict__ rbuf)
{
    __shared__ u16 lds[8192];   // 16 KiB
    const int bid = blockIdx.x;
    if (bid >= 3072) {
        const int rem = bid - 3072;
        transpose_tile(Wo, Wt + (size_t)3 * C_DIM * C_DIM, (rem & 63) * 32, (rem >> 6) * 32,
                       (float*)lds);
        return;
    }
    const int which = bid >> 10;
    const int b = bid & 1023;
    const int m0 = (b & 63) << 7;           // m-fast: XCD round-robin shares B panel
    const int n0 = (b >> 6) << 7;
    const u16* A = (which == 0) ? kx : (which == 1) ? vx : rxp;
    const u16* B = Wt + (size_t)which * C_DIM * C_DIM;
    u16* C = (which == 0) ? kbuf : (which == 1) ? vbuf : rbuf;
    gemm_core_sb(A, B, C, (which == 2) ? 2 : 1, C_DIM, C_DIM, m0, n0, lds);
}

__global__ __launch_bounds__(256, 4)
void gemm_o(const u16* __restrict__ Aw, const u16* __restrict__ Wt3,
            float* __restrict__ out, const float* __restrict__ x)
{
    __shared__ u16 lds[16384];  // 32 KiB
    const int m0 = (int)(blockIdx.x & 63) << 7;
    const int n0 = (int)(blockIdx.x >> 6) << 7;
    gemm_core_db(Aw, Wt3, out, x, C_DIM, C_DIM, m0, n0, lds);
}

// ---------------- WKV scan, chunked (k,v,r bf16) ----------------
__global__ __launch_bounds__(256)
void scan_partial(const u16* __restrict__ k, const u16* __restrict__ v,
                  const float* __restrict__ time_decay,
                  float* __restrict__ pA, float* __restrict__ pB, float* __restrict__ pP)
{
    const int c = blockIdx.y * 256 + threadIdx.x;
    const int j = blockIdx.x;
    const float w = -__expf(time_decay[c]);
    float aa = 0.f, bb = 0.f, pp = -1e30f;
    const u16* kp = k + (size_t)j * LCHUNK * C_DIM + c;
    const u16* vp = v + (size_t)j * LCHUNK * C_DIM + c;
#pragma unroll 4
    for (int i = 0; i < LCHUNK; ++i) {
        const float kk = bf2f(*kp);
        const float vv = bf2f(*vp);
        kp += C_DIM; vp += C_DIM;
        const float ww = w + pp;
        const float p2 = fmaxf(ww, kk);
        const float e1 = __expf(ww - p2);
        const float e2 = __expf(kk - p2);
        aa = e1 * aa + e2 * vv;
        bb = e1 * bb + e2;
        pp = p2;
    }
    const int o = j * C_DIM + c;
    pA[o] = aa; pB[o] = bb; pP[o] = pp;
}

__global__ __launch_bounds__(256)
void scan_combine(const float* __restrict__ pA, const float* __restrict__ pB,
                  const float* __restrict__ pP,
                  const float* __restrict__ aa_in, const float* __restrict__ bb_in,
                  const float* __restrict__ pp_in,
                  const float* __restrict__ time_decay,
                  float* __restrict__ sA, float* __restrict__ sB, float* __restrict__ sP)
{
    const int c = blockIdx.x * 256 + threadIdx.x;
    const float wL = -__expf(time_decay[c]) * (float)LCHUNK;
    float a = aa_in[c], b = bb_in[c], p = pp_in[c];
    for (int j = 0; j < NCHUNK; ++j) {
        const int o = j * C_DIM + c;
        sA[o] = a; sB[o] = b; sP[o] = p;
        const float A = pA[o], B = pB[o], P = pP[o];
        const float pd = p + wL;
        const float q = fmaxf(pd, P);
        const float e1 = __expf(pd - q), e2 = __expf(P - q);
        a = e1 * a + e2 * A;
        b = e1 * b + e2 * B;
        p = q;
    }
}

__global__ __launch_bounds__(256)
void scan_out(const u16* __restrict__ k, const u16* __restrict__ v,
              const u16* __restrict__ r,
              const float* __restrict__ time_decay, const float* __restrict__ time_first,
              const float* __restrict__ sA, const float* __restrict__ sB,
              const float* __restrict__ sP,
              u16* __restrict__ arwkv,
              float* __restrict__ aa_out, float* __restrict__ bb_out, float* __restrict__ pp_out)
{
    const int c = blockIdx.y * 256 + threadIdx.x;
    const int j = blockIdx.x;
    const float w = -__expf(time_decay[c]);
    const float u = time_first[c];
    const int so = j * C_DIM + c;
    float aa = sA[so], bb = sB[so], pp = sP[so];
    const size_t base = (size_t)j * LCHUNK * C_DIM + c;
    const u16* kp = k + base;
    const u16* vp = v + base;
    const u16* rp = r + base;
    u16* op = arwkv + base;
#pragma unroll 4
    for (int i = 0; i < LCHUNK; ++i) {
        const float kk = bf2f(*kp);
        const float vv = bf2f(*vp);
        const float sr = bf2f(*rp);
        kp += C_DIM; vp += C_DIM; rp += C_DIM;
        const float ww = u + kk;
        const float p = fmaxf(pp, ww);
        const float e1 = __expf(pp - p);
        const float e2 = __expf(ww - p);
        const float out = (e1 * aa + e2 * vv) / (e1 * bb + e2);
        *op = f2bf(sr * out);
        op += C_DIM;
        const float ww2 = w + pp;
        const float p2 = fmaxf(ww2, kk);
        const float f1 = __expf(ww2 - p2);
        const float f2 = __expf(kk - p2);
        aa = f1 * aa + f2 * vv;
        bb = f1 * bb + f2;
        pp = p2;
    }
    if (j == NCHUNK - 1) { aa_out[c] = aa; bb_out[c] = bb; pp_out[c] = pp; }
}

// ---------------- launcher ----------------
extern "C" void kernel_launch(void* const* d_in, const int* in_sizes, int n_in,
                              void* d_out, int out_size, void* d_ws, size_t ws_size,
                              hipStream_t stream)
{
    (void)in_sizes; (void)n_in; (void)out_size; (void)ws_size;
    const float* x          = (const float*)d_in[0];
    const float* sx         = (const float*)d_in[1];
    const float* aa_in      = (const float*)d_in[2];
    const float* bb_in      = (const float*)d_in[3];
    const float* pp_in      = (const float*)d_in[4];
    const float* time_first = (const float*)d_in[5];
    const float* time_decay = (const float*)d_in[6];
    const float* tmk        = (const float*)d_in[7];
    const float* tmv        = (const float*)d_in[8];
    const float* tmr        = (const float*)d_in[9];
    const float* lns        = (const float*)d_in[10];
    const float* lnb        = (const float*)d_in[11];
    const float* Wk         = (const float*)d_in[12];
    const float* Wv         = (const float*)d_in[13];
    const float* Wr         = (const float*)d_in[14];
    const float* Wo         = (const float*)d_in[15];

    float* out     = (float*)d_out;
    float* xx_last = out + (size_t)T_DIM * C_DIM;
    float* aa_out  = xx_last + C_DIM;
    float* bb_out  = aa_out + C_DIM;
    float* pp_out  = bb_out + C_DIM;

    const size_t TC = (size_t)T_DIM * C_DIM;
    const size_t C2 = (size_t)C_DIM * C_DIM;
    u16* kx    = (u16*)d_ws;
    u16* vx    = kx + TC;
    u16* rx    = vx + TC;
    u16* Wt    = rx + TC;                  // 4*C2 bf16
    u16* kbuf  = Wt + 4 * C2;              // TC bf16
    u16* vbuf  = kbuf + TC;                // TC bf16
    u16* rbuf  = vbuf + TC;                // TC bf16
    float* pA  = (float*)(rbuf + TC);
    float* pB  = pA + (size_t)NCHUNK * C_DIM;
    float* pP  = pB + (size_t)NCHUNK * C_DIM;
    float* sA  = pP + (size_t)NCHUNK * C_DIM;
    float* sB  = sA + (size_t)NCHUNK * C_DIM;
    float* sP  = sB + (size_t)NCHUNK * C_DIM;
    u16* arwkv = rx;   // alias: rx dead after gemm_kvr

    // d1: ln_mix U transpose Wk,Wv,Wr
    prep_kernel<<<8192 + 12288, 256, 0, stream>>>(Wk, Wv, Wr, Wt,
                                                  x, sx, lns, lnb, tmk, tmv, tmr,
                                                  kx, vx, rx, xx_last);
    // d2: k,v,r GEMMs (8 blocks/CU, single-buffered) U Wo transpose
    gemm_kvr<<<3072 + 4096, 256, 0, stream>>>(kx, vx, rx, Wo, Wt, kbuf, vbuf, rbuf);
    // d3-d5: chunked WKV scan
    scan_partial<<<dim3(NCHUNK, C_DIM / 256), 256, 0, stream>>>(kbuf, vbuf, time_decay, pA, pB, pP);
    scan_combine<<<C_DIM / 256, 256, 0, stream>>>(pA, pB, pP, aa_in, bb_in, pp_in, time_decay, sA, sB, sP);
    scan_out<<<dim3(NCHUNK, C_DIM / 256), 256, 0, stream>>>(kbuf, vbuf, rbuf, time_decay, time_first,
                                                            sA, sB, sP, arwkv, aa_out, bb_out, pp_out);
    // d6: output GEMM + residual (r8-proven dbuf core)
    gemm_o<<<1024, 256, 0, stream>>>(arwkv, Wt + 3 * C2, out, x);
}

// Round 11
// 458.773 us; speedup vs baseline: 7.4262x; 7.4262x over previous
//
#include <hip/hip_runtime.h>
#include <stdint.h>

#define T_DIM 8192
#define C_DIM 2048
#define LCHUNK 128
#define NCHUNK (T_DIM / LCHUNK)

typedef unsigned short u16;
typedef __bf16 bf16x8_t __attribute__((ext_vector_type(8)));
typedef float f32x4_t __attribute__((ext_vector_type(4)));

__device__ __forceinline__ u16 f2bf(float f) {
    union { float f; uint32_t u; } x; x.f = f;
    uint32_t r = x.u + 0x7fffu + ((x.u >> 16) & 1u);
    return (u16)(r >> 16);
}
__device__ __forceinline__ float bf2f(u16 u) {
    union { uint32_t u; float f; } x; x.u = ((uint32_t)u) << 16;
    return x.f;
}
__device__ __forceinline__ void gload16(const void* g, void* l) {
    __builtin_amdgcn_global_load_lds((const __attribute__((address_space(1))) uint32_t*)g,
                                     (__attribute__((address_space(3))) uint32_t*)l, 16, 0, 0);
}
__device__ __forceinline__ f32x4_t mfma16(bf16x8_t a, bf16x8_t b, f32x4_t c) {
    return __builtin_amdgcn_mfma_f32_16x16x32_bf16(a, b, c, 0, 0, 0);
}

// ---- shared helper: 32x32 weight transpose tile: Wt[n][k] = bf16(W[k][n]) ----
__device__ __forceinline__ void transpose_tile(const float* __restrict__ W, u16* __restrict__ Tm,
                                               int bn, int bk, float* shf)
{
    const int tid = threadIdx.x;
    const int tx = tid & 31, ty = tid >> 5;
#pragma unroll
    for (int i = 0; i < 4; ++i)
        shf[(ty + 8 * i) * 33 + tx] = W[(size_t)(bk + ty + 8 * i) * C_DIM + bn + tx];
    __syncthreads();
#pragma unroll
    for (int i = 0; i < 4; ++i)
        Tm[(size_t)(bn + ty + 8 * i) * C_DIM + bk + tx] = f2bf(shf[tx * 33 + ty + 8 * i]);
}

// ---------------- prep: ln_mix (blocks 0..8191) U transpose Wk,Wv,Wr (blocks 8192..20479) --------
union F8 { float4 v[2]; float f[8]; };

__global__ __launch_bounds__(256)
void prep_kernel(const float* __restrict__ W0, const float* __restrict__ W1,
                 const float* __restrict__ W2, u16* __restrict__ Wt,
                 const float* __restrict__ x, const float* __restrict__ sx,
                 const float* __restrict__ lns, const float* __restrict__ lnb,
                 const float* __restrict__ tmk, const float* __restrict__ tmv,
                 const float* __restrict__ tmr,
                 u16* __restrict__ kx, u16* __restrict__ vx, u16* __restrict__ rx,
                 float* __restrict__ xx_last)
{
    __shared__ float shf[32 * 33];
    const int bid = blockIdx.x;
    const int tid = threadIdx.x;

    if (bid >= 8192) {
        const int z = (bid - 8192) >> 12;
        const int rem = (bid - 8192) & 4095;
        const float* W = (z == 0) ? W0 : (z == 1) ? W1 : W2;
        transpose_tile(W, Wt + (size_t)z * C_DIM * C_DIM, (rem & 63) * 32, (rem >> 6) * 32, shf);
        return;
    }

    const int t = bid;
    const size_t rowoff = (size_t)t * C_DIM;

    F8 a, p;
    const float4* xt = (const float4*)(x + rowoff);
    a.v[0] = xt[2 * tid]; a.v[1] = xt[2 * tid + 1];
    const float4* xp = (t == 0) ? (const float4*)sx : (const float4*)(x + rowoff - C_DIM);
    p.v[0] = xp[2 * tid]; p.v[1] = xp[2 * tid + 1];

    float s1 = 0.f, s2 = 0.f, s3 = 0.f, s4 = 0.f;
#pragma unroll
    for (int i = 0; i < 8; ++i) {
        s1 += a.f[i]; s2 += a.f[i] * a.f[i];
        s3 += p.f[i]; s4 += p.f[i] * p.f[i];
    }
#pragma unroll
    for (int off = 32; off; off >>= 1) {
        s1 += __shfl_down(s1, off);
        s2 += __shfl_down(s2, off);
        s3 += __shfl_down(s3, off);
        s4 += __shfl_down(s4, off);
    }
    float* red = shf;
    if ((tid & 63) == 0) {
        red[0 * 4 + (tid >> 6)] = s1; red[1 * 4 + (tid >> 6)] = s2;
        red[2 * 4 + (tid >> 6)] = s3; red[3 * 4 + (tid >> 6)] = s4;
    }
    __syncthreads();
    s1 = red[0] + red[1] + red[2] + red[3];
    s2 = red[4] + red[5] + red[6] + red[7];
    s3 = red[8] + red[9] + red[10] + red[11];
    s4 = red[12] + red[13] + red[14] + red[15];
    const float inv = 1.0f / (float)C_DIM;
    const float mu = s1 * inv;
    const float rstd = rsqrtf(s2 * inv - mu * mu + 1e-5f);
    const float mup = s3 * inv;
    const float rstdp = rsqrtf(s4 * inv - mup * mup + 1e-5f);

    F8 ls, lb, mk, mv, mr;
    { const float4* q = (const float4*)lns; ls.v[0] = q[2*tid]; ls.v[1] = q[2*tid+1]; }
    { const float4* q = (const float4*)lnb; lb.v[0] = q[2*tid]; lb.v[1] = q[2*tid+1]; }
    { const float4* q = (const float4*)tmk; mk.v[0] = q[2*tid]; mk.v[1] = q[2*tid+1]; }
    { const float4* q = (const float4*)tmv; mv.v[0] = q[2*tid]; mv.v[1] = q[2*tid+1]; }
    { const float4* q = (const float4*)tmr; mr.v[0] = q[2*tid]; mr.v[1] = q[2*tid+1]; }

    union { u16 u[8]; uint4 q; } ok, ov, orr;
#pragma unroll
    for (int i = 0; i < 8; ++i) {
        const float xxv  = (a.f[i] - mu) * rstd * ls.f[i] + lb.f[i];
        const float prev = (t == 0) ? p.f[i] : (p.f[i] - mup) * rstdp * ls.f[i] + lb.f[i];
        ok.u[i]  = f2bf(xxv * mk.f[i] + prev * (1.f - mk.f[i]));
        ov.u[i]  = f2bf(xxv * mv.f[i] + prev * (1.f - mv.f[i]));
        orr.u[i] = f2bf(xxv * mr.f[i] + prev * (1.f - mr.f[i]));
        if (t == T_DIM - 1) xx_last[tid * 8 + i] = xxv;
    }
    ((uint4*)(kx + rowoff))[tid] = ok.q;
    ((uint4*)(vx + rowoff))[tid] = ov.q;
    ((uint4*)(rx + rowoff))[tid] = orr.q;
}

// ---------------- single-buffered GEMM core: 128x128 tile, BK=32, 16 KiB LDS ----------------
// m97 structure: stage -> sync -> ds_read+MFMA -> sync. Cross-iteration overlap comes from
// co-resident blocks. NO tight launch_bounds: with (256,4) the compiler keeps its natural
// ~56-80 VGPR (r9 measured 56, zero spill) and HW residency self-limits at
// min(LDS 160/16=10, wave slots 32/4=8, VGPR 512/56≈9) = 8 blocks/CU.
// (r10's (256,8) forced VGPR<=64 -> scratch spill -> 8.85 GB writes. Lesson learned.)
__device__ __forceinline__ void gemm_core_sb(
    const u16* __restrict__ A, const u16* __restrict__ Bt,
    void* __restrict__ Cout, const int mode, const int N, const int K,
    const int m0, const int n0, u16* lds)
{
    const int tid = threadIdx.x;
    const int wave = tid >> 6, lane = tid & 63;
    const int wm = wave >> 1, wn = wave & 1;
    const int fr = lane & 15, fo = lane >> 4;
    const int sw = (fo ^ ((fr >> 1) & 3)) * 8;

    f32x4_t acc[4][4] = {};

    const int lrow = lane >> 2;
    const int scol = ((lane & 3) ^ ((lane >> 3) & 3)) * 8;
    const u16* gA = A  + (size_t)(m0 + wave * 16 + lrow) * K + scol;
    const u16* gB = Bt + (size_t)(n0 + wave * 16 + lrow) * K + scol;
    const size_t rk64 = (size_t)64 * K;
    const int dA = wave * 512;
    const int dB = 4096 + wave * 512;

    const int NT = K >> 5;
    for (int t = 0; t < NT; ++t) {
        const u16* ga = gA + (size_t)t * 32;
        const u16* gb = gB + (size_t)t * 32;
        gload16(ga,        lds + dA);
        gload16(ga + rk64, lds + dA + 2048);
        gload16(gb,        lds + dB);
        gload16(gb + rk64, lds + dB + 2048);
        __syncthreads();                       // stage landed (vmcnt0 + barrier)
        const u16* lA = lds + (wm * 64 + fr) * 32;
        const u16* lB = lds + 4096 + (wn * 64 + fr) * 32;
        bf16x8_t a[4], b[4];
#pragma unroll
        for (int i = 0; i < 4; ++i) {
            a[i] = *(const bf16x8_t*)(lA + i * 512 + sw);
            b[i] = *(const bf16x8_t*)(lB + i * 512 + sw);
        }
        __builtin_amdgcn_s_setprio(1);
#pragma unroll
        for (int mi = 0; mi < 4; ++mi)
#pragma unroll
            for (int ni = 0; ni < 4; ++ni)
                acc[mi][ni] = mfma16(a[mi], b[ni], acc[mi][ni]);
        __builtin_amdgcn_s_setprio(0);
        __syncthreads();                       // all ds_reads consumed before next stage
    }

    const int r4 = fo * 4;
#pragma unroll
    for (int mi = 0; mi < 4; ++mi) {
#pragma unroll
        for (int ni = 0; ni < 4; ++ni) {
            const int col = n0 + wn * 64 + ni * 16 + fr;
#pragma unroll
            for (int i = 0; i < 4; ++i) {
                const int row = m0 + wm * 64 + mi * 16 + r4 + i;
                float v = acc[mi][ni][i];
                if (mode == 1) ((u16*)Cout)[(size_t)row * N + col] = f2bf(v);
                else {
                    const float s = 1.f / (1.f + __expf(-v));
                    ((u16*)Cout)[(size_t)row * N + col] = f2bf(s);
                }
            }
        }
    }
}

// ---------------- dbuf GEMM core (r8-proven, 32 KiB, 4 blocks/CU) for gemm_o ----------------
__device__ __forceinline__ void gemm_core_db(
    const u16* __restrict__ A, const u16* __restrict__ Bt,
    float* __restrict__ Cout, const float* __restrict__ resid,
    const int N, const int K, const int m0, const int n0, u16* lds)
{
    const int tid = threadIdx.x;
    const int wave = tid >> 6, lane = tid & 63;
    const int wm = wave >> 1, wn = wave & 1;
    const int fr = lane & 15, fo = lane >> 4;
    const int sw = (fo ^ ((fr >> 1) & 3)) * 8;

    f32x4_t acc[4][4] = {};

    const int lrow = lane >> 2;
    const int scol = ((lane & 3) ^ ((lane >> 3) & 3)) * 8;
    const u16* gA = A  + (size_t)(m0 + wave * 16 + lrow) * K + scol;
    const u16* gB = Bt + (size_t)(n0 + wave * 16 + lrow) * K + scol;
    const size_t rk64 = (size_t)64 * K;
    const int dA = wave * 512;
    const int dB = 4096 + wave * 512;

    auto stage = [&](int t) {
        const int b = (t & 1) * 8192;
        const u16* ga = gA + (size_t)t * 32;
        const u16* gb = gB + (size_t)t * 32;
        gload16(ga,        lds + b + dA);
        gload16(ga + rk64, lds + b + dA + 2048);
        gload16(gb,        lds + b + dB);
        gload16(gb + rk64, lds + b + dB + 2048);
    };

    const int NT = K >> 5;
    stage(0);
    asm volatile("s_waitcnt vmcnt(0)" ::: "memory");
    asm volatile("s_barrier" ::: "memory");

    for (int t = 0; t < NT; ++t) {
        if (t + 1 < NT) stage(t + 1);
        const u16* lA = lds + (t & 1) * 8192 + (wm * 64 + fr) * 32;
        const u16* lB = lds + (t & 1) * 8192 + 4096 + (wn * 64 + fr) * 32;
        bf16x8_t a[4], b[4];
#pragma unroll
        for (int i = 0; i < 4; ++i) {
            a[i] = *(const bf16x8_t*)(lA + i * 512 + sw);
            b[i] = *(const bf16x8_t*)(lB + i * 512 + sw);
        }
        __builtin_amdgcn_s_setprio(1);
#pragma unroll
        for (int mi = 0; mi < 4; ++mi)
#pragma unroll
            for (int ni = 0; ni < 4; ++ni)
                acc[mi][ni] = mfma16(a[mi], b[ni], acc[mi][ni]);
        __builtin_amdgcn_s_setprio(0);
        asm volatile("s_waitcnt vmcnt(0)" ::: "memory");
        asm volatile("s_barrier" ::: "memory");
    }

    const int r4 = fo * 4;
#pragma unroll
    for (int mi = 0; mi < 4; ++mi) {
#pragma unroll
        for (int ni = 0; ni < 4; ++ni) {
            const int col = n0 + wn * 64 + ni * 16 + fr;
#pragma unroll
            for (int i = 0; i < 4; ++i) {
                const int row = m0 + wm * 64 + mi * 16 + r4 + i;
                Cout[(size_t)row * N + col] = acc[mi][ni][i] + resid[(size_t)row * N + col];
            }
        }
    }
}

// k,v,r GEMMs (blocks 0..3071) U Wo transpose (blocks 3072..7167).
// launch_bounds (256,4): VGPR target 128 (no spill); residency self-limits at ~8 blocks/CU.
__global__ __launch_bounds__(256, 4)
void gemm_kvr(const u16* __restrict__ kx, const u16* __restrict__ vx, const u16* __restrict__ rxp,
              const float* __restrict__ Wo, u16* __restrict__ Wt,
              u16* __restrict__ kbuf, u16* __restrict__ vbuf, u16* __restrict__ rbuf)
{
    __shared__ u16 lds[8192];   // 16 KiB
    const int bid = blockIdx.x;
    if (bid >= 3072) {
        const int rem = bid - 3072;
        transpose_tile(Wo, Wt + (size_t)3 * C_DIM * C_DIM, (rem & 63) * 32, (rem >> 6) * 32,
                       (float*)lds);
        return;
    }
    const int which = bid >> 10;
    const int b = bid & 1023;
    const int m0 = (b & 63) << 7;           // m-fast: XCD round-robin shares B panel
    const int n0 = (b >> 6) << 7;
    const u16* A = (which == 0) ? kx : (which == 1) ? vx : rxp;
    const u16* B = Wt + (size_t)which * C_DIM * C_DIM;
    u16* C = (which == 0) ? kbuf : (which == 1) ? vbuf : rbuf;
    gemm_core_sb(A, B, C, (which == 2) ? 2 : 1, C_DIM, C_DIM, m0, n0, lds);
}

__global__ __launch_bounds__(256, 4)
void gemm_o(const u16* __restrict__ Aw, const u16* __restrict__ Wt3,
            float* __restrict__ out, const float* __restrict__ x)
{
    __shared__ u16 lds[16384];  // 32 KiB
    const int m0 = (int)(blockIdx.x & 63) << 7;
    const int n0 = (int)(blockIdx.x >> 6) << 7;
    gemm_core_db(Aw, Wt3, out, x, C_DIM, C_DIM, m0, n0, lds);
}

// ---------------- WKV scan, chunked (k,v,r bf16) ----------------
__global__ __launch_bounds__(256)
void scan_partial(const u16* __restrict__ k, const u16* __restrict__ v,
                  const float* __restrict__ time_decay,
                  float* __restrict__ pA, float* __restrict__ pB, float* __restrict__ pP)
{
    const int c = blockIdx.y * 256 + threadIdx.x;
    const int j = blockIdx.x;
    const float w = -__expf(time_decay[c]);
    float aa = 0.f, bb = 0.f, pp = -1e30f;
    const u16* kp = k + (size_t)j * LCHUNK * C_DIM + c;
    const u16* vp = v + (size_t)j * LCHUNK * C_DIM + c;
#pragma unroll 4
    for (int i = 0; i < LCHUNK; ++i) {
        const float kk = bf2f(*kp);
        const float vv = bf2f(*vp);
        kp += C_DIM; vp += C_DIM;
        const float ww = w + pp;
        const float p2 = fmaxf(ww, kk);
        const float e1 = __expf(ww - p2);
        const float e2 = __expf(kk - p2);
        aa = e1 * aa + e2 * vv;
        bb = e1 * bb + e2;
        pp = p2;
    }
    const int o = j * C_DIM + c;
    pA[o] = aa; pB[o] = bb; pP[o] = pp;
}

__global__ __launch_bounds__(256)
void scan_combine(const float* __restrict__ pA, const float* __restrict__ pB,
                  const float* __restrict__ pP,
                  const float* __restrict__ aa_in, const float* __restrict__ bb_in,
                  const float* __restrict__ pp_in,
                  const float* __restrict__ time_decay,
                  float* __restrict__ sA, float* __restrict__ sB, float* __restrict__ sP)
{
    const int c = blockIdx.x * 256 + threadIdx.x;
    const float wL = -__expf(time_decay[c]) * (float)LCHUNK;
    float a = aa_in[c], b = bb_in[c], p = pp_in[c];
    for (int j = 0; j < NCHUNK; ++j) {
        const int o = j * C_DIM + c;
        sA[o] = a; sB[o] = b; sP[o] = p;
        const float A = pA[o], B = pB[o], P = pP[o];
        const float pd = p + wL;
        const float q = fmaxf(pd, P);
        const float e1 = __expf(pd - q), e2 = __expf(P - q);
        a = e1 * a + e2 * A;
        b = e1 * b + e2 * B;
        p = q;
    }
}

__global__ __launch_bounds__(256)
void scan_out(const u16* __restrict__ k, const u16* __restrict__ v,
              const u16* __restrict__ r,
              const float* __restrict__ time_decay, const float* __restrict__ time_first,
              const float* __restrict__ sA, const float* __restrict__ sB,
              const float* __restrict__ sP,
              u16* __restrict__ arwkv,
              float* __restrict__ aa_out, float* __restrict__ bb_out, float* __restrict__ pp_out)
{
    const int c = blockIdx.y * 256 + threadIdx.x;
    const int j = blockIdx.x;
    const float w = -__expf(time_decay[c]);
    const float u = time_first[c];
    const int so = j * C_DIM + c;
    float aa = sA[so], bb = sB[so], pp = sP[so];
    const size_t base = (size_t)j * LCHUNK * C_DIM + c;
    const u16* kp = k + base;
    const u16* vp = v + base;
    const u16* rp = r + base;
    u16* op = arwkv + base;
#pragma unroll 4
    for (int i = 0; i < LCHUNK; ++i) {
        const float kk = bf2f(*kp);
        const float vv = bf2f(*vp);
        const float sr = bf2f(*rp);
        kp += C_DIM; vp += C_DIM; rp += C_DIM;
        const float ww = u + kk;
        const float p = fmaxf(pp, ww);
        const float e1 = __expf(pp - p);
        const float e2 = __expf(ww - p);
        const float out = (e1 * aa + e2 * vv) / (e1 * bb + e2);
        *op = f2bf(sr * out);
        op += C_DIM;
        const float ww2 = w + pp;
        const float p2 = fmaxf(ww2, kk);
        const float f1 = __expf(ww2 - p2);
        const float f2 = __expf(kk - p2);
        aa = f1 * aa + f2 * vv;
        bb = f1 * bb + f2;
        pp = p2;
    }
    if (j == NCHUNK - 1) { aa_out[c] = aa; bb_out[c] = bb; pp_out[c] = pp; }
}

// ---------------- launcher ----------------
extern "C" void kernel_launch(void* const* d_in, const int* in_sizes, int n_in,
                              void* d_out, int out_size, void* d_ws, size_t ws_size,
                              hipStream_t stream)
{
    (void)in_sizes; (void)n_in; (void)out_size; (void)ws_size;
    const float* x          = (const float*)d_in[0];
    const float* sx         = (const float*)d_in[1];
    const float* aa_in      = (const float*)d_in[2];
    const float* bb_in      = (const float*)d_in[3];
    const float* pp_in      = (const float*)d_in[4];
    const float* time_first = (const float*)d_in[5];
    const float* time_decay = (const float*)d_in[6];
    const float* tmk        = (const float*)d_in[7];
    const float* tmv        = (const float*)d_in[8];
    const float* tmr        = (const float*)d_in[9];
    const float* lns        = (const float*)d_in[10];
    const float* lnb        = (const float*)d_in[11];
    const float* Wk         = (const float*)d_in[12];
    const float* Wv         = (const float*)d_in[13];
    const float* Wr         = (const float*)d_in[14];
    const float* Wo         = (const float*)d_in[15];

    float* out     = (float*)d_out;
    float* xx_last = out + (size_t)T_DIM * C_DIM;
    float* aa_out  = xx_last + C_DIM;
    float* bb_out  = aa_out + C_DIM;
    float* pp_out  = bb_out + C_DIM;

    const size_t TC = (size_t)T_DIM * C_DIM;
    const size_t C2 = (size_t)C_DIM * C_DIM;
    u16* kx    = (u16*)d_ws;
    u16* vx    = kx + TC;
    u16* rx    = vx + TC;
    u16* Wt    = rx + TC;                  // 4*C2 bf16
    u16* kbuf  = Wt + 4 * C2;              // TC bf16
    u16* vbuf  = kbuf + TC;                // TC bf16
    u16* rbuf  = vbuf + TC;                // TC bf16
    float* pA  = (float*)(rbuf + TC);
    float* pB  = pA + (size_t)NCHUNK * C_DIM;
    float* pP  = pB + (size_t)NCHUNK * C_DIM;
    float* sA  = pP + (size_t)NCHUNK * C_DIM;
    float* sB  = sA + (size_t)NCHUNK * C_DIM;
    float* sP  = sB + (size_t)NCHUNK * C_DIM;
    u16* arwkv = rx;   // alias: rx dead after gemm_kvr

    // d1: ln_mix U transpose Wk,Wv,Wr
    prep_kernel<<<8192 + 12288, 256, 0, stream>>>(Wk, Wv, Wr, Wt,
                                                  x, sx, lns, lnb, tmk, tmv, tmr,
                                                  kx, vx, rx, xx_last);
    // d2: k,v,r GEMMs (single-buffered 16 KiB, natural VGPR, ~8 blocks/CU) U Wo transpose
    gemm_kvr<<<3072 + 4096, 256, 0, stream>>>(kx, vx, rx, Wo, Wt, kbuf, vbuf, rbuf);
    // d3-d5: chunked WKV scan
    scan_partial<<<dim3(NCHUNK, C_DIM / 256), 256, 0, stream>>>(kbuf, vbuf, time_decay, pA, pB, pP);
    scan_combine<<<C_DIM / 256, 256, 0, stream>>>(pA, pB, pP, aa_in, bb_in, pp_in, time_decay, sA, sB, sP);
    scan_out<<<dim3(NCHUNK, C_DIM / 256), 256, 0, stream>>>(kbuf, vbuf, rbuf, time_decay, time_first,
                                                            sA, sB, sP, arwkv, aa_out, bb_out, pp_out);
    // d6: output GEMM + residual (r8-proven dbuf core)
    gemm_o<<<1024, 256, 0, stream>>>(arwkv, Wt + 3 * C2, out, x);
}